// Round 1
// baseline (343.537 us; speedup 1.0000x reference)
//
#include <hip/hip_runtime.h>
#include <stdint.h>

#define D_DIM 512
#define MAX_RADIUS 3.0f
#define EPS 1e-8f

#define BM 128
#define BN 128
#define BK 32

typedef __bf16 bf16x8 __attribute__((ext_vector_type(8)));
typedef float f32x4 __attribute__((ext_vector_type(4)));

#define GLOBAL_AS __attribute__((address_space(1)))
#define LDS_AS __attribute__((address_space(3)))

static __device__ __forceinline__ unsigned short f2bf(float f) {
  union { float f; uint32_t u; } v; v.f = f;
  uint32_t u = v.u;
  uint32_t r = (u + 0x7fffu + ((u >> 16) & 1u)) >> 16;  // RNE
  return (unsigned short)r;
}

// ---------------- zero accumulators ----------------
__global__ void zero2_f32(float* __restrict__ a, float* __restrict__ b, int n) {
  int i = blockIdx.x * blockDim.x + threadIdx.x;
  if (i < n) { a[i] = 0.0f; b[i] = 0.0f; }
}

__global__ void zero_out(float* out) {
  if (threadIdx.x == 0 && blockIdx.x == 0) out[0] = 0.0f;
}

// ------------- f32 -> bf16 convert + row squared-norms -------------
// one wave per row (D=512 -> 8 f32 per lane)
__global__ __launch_bounds__(256) void convert_rows(const float* __restrict__ src,
                                                    unsigned short* __restrict__ dst,
                                                    float* __restrict__ norms, int nrows) {
  int wid = threadIdx.x >> 6;
  int lane = threadIdx.x & 63;
  int row = blockIdx.x * 4 + wid;
  if (row >= nrows) return;
  const float4* s4 = reinterpret_cast<const float4*>(src + (size_t)row * D_DIM + lane * 8);
  float4 a = s4[0], b = s4[1];
  float ss = a.x*a.x + a.y*a.y + a.z*a.z + a.w*a.w
           + b.x*b.x + b.y*b.y + b.z*b.z + b.w*b.w;
  uint4 o;
  o.x = (uint32_t)f2bf(a.x) | ((uint32_t)f2bf(a.y) << 16);
  o.y = (uint32_t)f2bf(a.z) | ((uint32_t)f2bf(a.w) << 16);
  o.z = (uint32_t)f2bf(b.x) | ((uint32_t)f2bf(b.y) << 16);
  o.w = (uint32_t)f2bf(b.z) | ((uint32_t)f2bf(b.w) << 16);
  *reinterpret_cast<uint4*>(dst + (size_t)row * D_DIM + lane * 8) = o;
#pragma unroll
  for (int s = 1; s < 64; s <<= 1) ss += __shfl_xor(ss, s, 64);
  if (lane == 0) norms[row] = ss;
}

// ------------- bf16 MFMA GEMM (X·Y^T) + fused RBF epilogue -------------
// m97 structure: 128x128 tile, 4 waves (2x2), each wave 64x64 = 4x4 MFMA frags,
// global_load_lds width-16 staging, 2 barriers per K-step.
__global__ __launch_bounds__(256) void gemm_epilogue(
    const unsigned short* __restrict__ Xb, const unsigned short* __restrict__ Yb,
    const float* __restrict__ x2, const float* __restrict__ y2,
    float* __restrict__ wsum, float* __restrict__ wdsum, int Ntiles) {
  __shared__ __align__(16) unsigned short As[BM * BK];
  __shared__ __align__(16) unsigned short Bs[BN * BK];

  int bid = blockIdx.x;
  int mt = bid / Ntiles;
  int nt = bid % Ntiles;
  int m0 = mt * BM, n0 = nt * BN;
  int tid = threadIdx.x;
  int lane = tid & 63;
  int wid = tid >> 6;
  int wm = wid >> 1, wn = wid & 1;  // 2x2 waves, 64x64 each
  int lg = lane >> 4;               // 0..3 (k-group for frags / row-group for C)
  int lr = lane & 15;               // row-in-16 for frags / col for C

  f32x4 acc[4][4];
#pragma unroll
  for (int i = 0; i < 4; ++i)
#pragma unroll
    for (int j = 0; j < 4; ++j) acc[i][j] = (f32x4){0.f, 0.f, 0.f, 0.f};

  // staging map: byte t*16 of the 8KB tile -> row t/4, bf16-col (t%4)*8
  int arow = tid >> 2;
  int acol = (tid & 3) * 8;
  const unsigned short* gA  = Xb + (size_t)(m0 + arow) * D_DIM + acol;
  const unsigned short* gB  = Yb + (size_t)(n0 + arow) * D_DIM + acol;
  const unsigned short* gA2 = gA + (size_t)64 * D_DIM;
  const unsigned short* gB2 = gB + (size_t)64 * D_DIM;
  unsigned short* lA  = &As[arow * BK + acol];
  unsigned short* lB  = &Bs[arow * BK + acol];
  unsigned short* lA2 = lA + 64 * BK;
  unsigned short* lB2 = lB + 64 * BK;

  for (int k0 = 0; k0 < D_DIM; k0 += BK) {
    __builtin_amdgcn_global_load_lds((const GLOBAL_AS uint32_t*)gA,  (LDS_AS uint32_t*)lA,  16, 0, 0);
    __builtin_amdgcn_global_load_lds((const GLOBAL_AS uint32_t*)gA2, (LDS_AS uint32_t*)lA2, 16, 0, 0);
    __builtin_amdgcn_global_load_lds((const GLOBAL_AS uint32_t*)gB,  (LDS_AS uint32_t*)lB,  16, 0, 0);
    __builtin_amdgcn_global_load_lds((const GLOBAL_AS uint32_t*)gB2, (LDS_AS uint32_t*)lB2, 16, 0, 0);
    gA += BK; gA2 += BK; gB += BK; gB2 += BK;
    __syncthreads();  // drains vmcnt -> LDS tiles ready

    bf16x8 af[4], bfv[4];
#pragma unroll
    for (int f = 0; f < 4; ++f) {
      af[f]  = *reinterpret_cast<const bf16x8*>(&As[(wm * 64 + f * 16 + lr) * BK + lg * 8]);
      bfv[f] = *reinterpret_cast<const bf16x8*>(&Bs[(wn * 64 + f * 16 + lr) * BK + lg * 8]);
    }
#pragma unroll
    for (int i = 0; i < 4; ++i)
#pragma unroll
      for (int j = 0; j < 4; ++j)
        acc[i][j] = __builtin_amdgcn_mfma_f32_16x16x32_bf16(af[i], bfv[j], acc[i][j], 0, 0, 0);
    __syncthreads();  // all reads done before next stage overwrites
  }

  // epilogue: d2 = x2 + y2 - 2c; w = exp(-d2); accumulate per-row (w, w*d)
  float y2v[4];
#pragma unroll
  for (int j = 0; j < 4; ++j) y2v[j] = y2[n0 + wn * 64 + j * 16 + lr];

#pragma unroll
  for (int i = 0; i < 4; ++i) {
#pragma unroll
    for (int r = 0; r < 4; ++r) {
      int m = m0 + wm * 64 + i * 16 + lg * 4 + r;  // C/D: row=(lane>>4)*4+reg
      float xv = x2[m];
      float wsp = 0.f, wdp = 0.f;
#pragma unroll
      for (int j = 0; j < 4; ++j) {
        float c = acc[i][j][r];
        float d2 = fmaxf(xv + y2v[j] - 2.0f * c, 0.0f);
        float d = sqrtf(d2);
        float w = __expf(-d2);
        wsp += w;
        wdp = fmaf(w, d, wdp);
      }
      // reduce across the 16 lanes sharing this row (same lane>>4)
#pragma unroll
      for (int s = 1; s < 16; s <<= 1) {
        wsp += __shfl_xor(wsp, s, 64);
        wdp += __shfl_xor(wdp, s, 64);
      }
      if (lr == 0) {
        atomicAdd(&wsum[m], wsp);
        atomicAdd(&wdsum[m], wdp);
      }
    }
  }
}

// ------------- finalize: soft-distance, cap, -mean -------------
__global__ __launch_bounds__(256) void finalize(const float* __restrict__ wsum,
                                                const float* __restrict__ wdsum,
                                                float* __restrict__ out, int M) {
  __shared__ float red[256];
  float acc = 0.f;
  for (int r = threadIdx.x; r < M; r += 256) {
    float soft = wdsum[r] / (wsum[r] + EPS);
    acc += fminf(soft, MAX_RADIUS);
  }
  red[threadIdx.x] = acc;
  __syncthreads();
  for (int s = 128; s > 0; s >>= 1) {
    if (threadIdx.x < s) red[threadIdx.x] += red[threadIdx.x + s];
    __syncthreads();
  }
  if (threadIdx.x == 0) out[0] = -red[0] / (float)M;
}

// ------------- workspace-free fallback (insurance if ws too small) -------------
__global__ __launch_bounds__(256) void fallback_row(const float* __restrict__ X,
                                                    const float* __restrict__ Y,
                                                    float* __restrict__ out, int M, int N) {
  __shared__ float xs[D_DIM];
  __shared__ float red[512];
  int b = blockIdx.x;
  for (int i = threadIdx.x; i < D_DIM; i += 256) xs[i] = X[(size_t)b * D_DIM + i];
  __syncthreads();
  float ws = 0.f, wd = 0.f;
  for (int k = threadIdx.x; k < N; k += 256) {
    const float4* y4 = reinterpret_cast<const float4*>(Y + (size_t)k * D_DIM);
    float d2 = 0.f;
#pragma unroll 8
    for (int j = 0; j < D_DIM / 4; ++j) {
      float4 yv = y4[j];
      float4 xv = *reinterpret_cast<const float4*>(&xs[j * 4]);
      float dx = xv.x - yv.x, dy = xv.y - yv.y, dz = xv.z - yv.z, dw = xv.w - yv.w;
      d2 += dx * dx + dy * dy + dz * dz + dw * dw;
    }
    float d = sqrtf(d2);
    float w = __expf(-d2);
    ws += w; wd = fmaf(w, d, wd);
  }
  red[threadIdx.x] = ws; red[256 + threadIdx.x] = wd;
  __syncthreads();
  for (int s = 128; s > 0; s >>= 1) {
    if (threadIdx.x < s) {
      red[threadIdx.x] += red[threadIdx.x + s];
      red[256 + threadIdx.x] += red[256 + threadIdx.x + s];
    }
    __syncthreads();
  }
  if (threadIdx.x == 0) {
    float soft = red[256] / (red[0] + EPS);
    atomicAdd(out, -fminf(soft, MAX_RADIUS) / (float)M);
  }
}

extern "C" void kernel_launch(void* const* d_in, const int* in_sizes, int n_in,
                              void* d_out, int out_size, void* d_ws, size_t ws_size,
                              hipStream_t stream) {
  const float* X = (const float*)d_in[0];  // z_generated [M,512]
  const float* Y = (const float*)d_in[1];  // z_known [N,512]
  float* out = (float*)d_out;
  int M = in_sizes[0] / D_DIM;
  int N = in_sizes[1] / D_DIM;

  auto align256 = [](size_t x) { return (x + 255) & ~(size_t)255; };
  size_t oXb = 0;
  size_t oYb = align256(oXb + (size_t)M * D_DIM * 2);
  size_t ox2 = align256(oYb + (size_t)N * D_DIM * 2);
  size_t oy2 = align256(ox2 + (size_t)M * 4);
  size_t ows = align256(oy2 + (size_t)N * 4);
  size_t owd = align256(ows + (size_t)M * 4);
  size_t need = owd + (size_t)M * 4;

  bool fast = (ws_size >= need) && (M % BM == 0) && (N % BN == 0);
  if (fast) {
    char* ws = (char*)d_ws;
    unsigned short* Xb = (unsigned short*)(ws + oXb);
    unsigned short* Yb = (unsigned short*)(ws + oYb);
    float* x2 = (float*)(ws + ox2);
    float* y2 = (float*)(ws + oy2);
    float* wsv = (float*)(ws + ows);
    float* wdv = (float*)(ws + owd);

    zero2_f32<<<(M + 255) / 256, 256, 0, stream>>>(wsv, wdv, M);
    convert_rows<<<(M + 3) / 4, 256, 0, stream>>>(X, Xb, x2, M);
    convert_rows<<<(N + 3) / 4, 256, 0, stream>>>(Y, Yb, y2, N);
    int Mtiles = M / BM, Ntiles = N / BN;
    gemm_epilogue<<<Mtiles * Ntiles, 256, 0, stream>>>(Xb, Yb, x2, y2, wsv, wdv, Ntiles);
    finalize<<<1, 256, 0, stream>>>(wsv, wdv, out, M);
  } else {
    zero_out<<<1, 64, 0, stream>>>(out);
    fallback_row<<<M, 256, 0, stream>>>(X, Y, out, M, N);
  }
}

// Round 2
// 112.491 us; speedup vs baseline: 3.0539x; 3.0539x over previous
//
#include <hip/hip_runtime.h>
#include <stdint.h>

#define D_DIM 512
#define MAX_RADIUS 3.0f
#define EPS 1e-8f

// exp(-d2) in f32 is exactly 0 (even with denormals) once d2*log2(e) > 150,
// i.e. d2 > ~104. Elements with d2 >= EXP_CUTOFF contribute exactly 0 to both
// w_sum and w*d sums, so they can be skipped without changing the result.
#define EXP_CUTOFF 104.0f

#define BM 128
#define BN 128
#define BK 32

typedef __bf16 bf16x8 __attribute__((ext_vector_type(8)));
typedef float f32x4 __attribute__((ext_vector_type(4)));

#define GLOBAL_AS __attribute__((address_space(1)))
#define LDS_AS __attribute__((address_space(3)))

static __device__ __forceinline__ unsigned short f2bf(float f) {
  union { float f; uint32_t u; } v; v.f = f;
  uint32_t u = v.u;
  uint32_t r = (u + 0x7fffu + ((u >> 16) & 1u)) >> 16;  // RNE
  return (unsigned short)r;
}

// ---------------- zero accumulators ----------------
__global__ void zero2_f32(float* __restrict__ a, float* __restrict__ b, int n) {
  int i = blockIdx.x * blockDim.x + threadIdx.x;
  if (i < n) { a[i] = 0.0f; b[i] = 0.0f; }
}

__global__ void zero_out(float* out) {
  if (threadIdx.x == 0 && blockIdx.x == 0) out[0] = 0.0f;
}

// ------------- f32 -> bf16 convert + row squared-norms -------------
// one wave per row (D=512 -> 8 f32 per lane)
__global__ __launch_bounds__(256) void convert_rows(const float* __restrict__ src,
                                                    unsigned short* __restrict__ dst,
                                                    float* __restrict__ norms, int nrows) {
  int wid = threadIdx.x >> 6;
  int lane = threadIdx.x & 63;
  int row = blockIdx.x * 4 + wid;
  if (row >= nrows) return;
  const float4* s4 = reinterpret_cast<const float4*>(src + (size_t)row * D_DIM + lane * 8);
  float4 a = s4[0], b = s4[1];
  float ss = a.x*a.x + a.y*a.y + a.z*a.z + a.w*a.w
           + b.x*b.x + b.y*b.y + b.z*b.z + b.w*b.w;
  uint4 o;
  o.x = (uint32_t)f2bf(a.x) | ((uint32_t)f2bf(a.y) << 16);
  o.y = (uint32_t)f2bf(a.z) | ((uint32_t)f2bf(a.w) << 16);
  o.z = (uint32_t)f2bf(b.x) | ((uint32_t)f2bf(b.y) << 16);
  o.w = (uint32_t)f2bf(b.z) | ((uint32_t)f2bf(b.w) << 16);
  *reinterpret_cast<uint4*>(dst + (size_t)row * D_DIM + lane * 8) = o;
#pragma unroll
  for (int s = 1; s < 64; s <<= 1) ss += __shfl_xor(ss, s, 64);
  if (lane == 0) norms[row] = ss;
}

// ------------- bf16 MFMA GEMM (X·Y^T) + fused RBF epilogue -------------
// m97 structure: 128x128 tile, 4 waves (2x2), each wave 64x64 = 4x4 MFMA frags,
// global_load_lds width-16 staging, 2 barriers per K-step.
// Epilogue: conservative bound d2_min >= x2_min + y2_min - 2*max(c); if no lane
// in the wave can produce d2 < EXP_CUTOFF, the entire exp/sqrt/reduce/atomic
// path is skipped (contribution is exactly 0).
__global__ __launch_bounds__(256) void gemm_epilogue(
    const unsigned short* __restrict__ Xb, const unsigned short* __restrict__ Yb,
    const float* __restrict__ x2, const float* __restrict__ y2,
    float* __restrict__ wsum, float* __restrict__ wdsum, int Ntiles) {
  __shared__ __align__(16) unsigned short As[BM * BK];
  __shared__ __align__(16) unsigned short Bs[BN * BK];

  int bid = blockIdx.x;
  int mt = bid / Ntiles;
  int nt = bid % Ntiles;
  int m0 = mt * BM, n0 = nt * BN;
  int tid = threadIdx.x;
  int lane = tid & 63;
  int wid = tid >> 6;
  int wm = wid >> 1, wn = wid & 1;  // 2x2 waves, 64x64 each
  int lg = lane >> 4;               // 0..3 (k-group for frags / row-group for C)
  int lr = lane & 15;               // row-in-16 for frags / col for C

  f32x4 acc[4][4];
#pragma unroll
  for (int i = 0; i < 4; ++i)
#pragma unroll
    for (int j = 0; j < 4; ++j) acc[i][j] = (f32x4){0.f, 0.f, 0.f, 0.f};

  // staging map: byte t*16 of the 8KB tile -> row t/4, bf16-col (t%4)*8
  // (lane l of wave w lands at byte w*1024 + l*16 -> wave-uniform+lane*16: OK)
  int arow = tid >> 2;
  int acol = (tid & 3) * 8;
  const unsigned short* gA  = Xb + (size_t)(m0 + arow) * D_DIM + acol;
  const unsigned short* gB  = Yb + (size_t)(n0 + arow) * D_DIM + acol;
  const unsigned short* gA2 = gA + (size_t)64 * D_DIM;
  const unsigned short* gB2 = gB + (size_t)64 * D_DIM;
  unsigned short* lA  = &As[arow * BK + acol];
  unsigned short* lB  = &Bs[arow * BK + acol];
  unsigned short* lA2 = lA + 64 * BK;
  unsigned short* lB2 = lB + 64 * BK;

  for (int k0 = 0; k0 < D_DIM; k0 += BK) {
    __builtin_amdgcn_global_load_lds((const GLOBAL_AS uint32_t*)gA,  (LDS_AS uint32_t*)lA,  16, 0, 0);
    __builtin_amdgcn_global_load_lds((const GLOBAL_AS uint32_t*)gA2, (LDS_AS uint32_t*)lA2, 16, 0, 0);
    __builtin_amdgcn_global_load_lds((const GLOBAL_AS uint32_t*)gB,  (LDS_AS uint32_t*)lB,  16, 0, 0);
    __builtin_amdgcn_global_load_lds((const GLOBAL_AS uint32_t*)gB2, (LDS_AS uint32_t*)lB2, 16, 0, 0);
    gA += BK; gA2 += BK; gB += BK; gB2 += BK;
    __syncthreads();  // drains vmcnt -> LDS tiles ready

    bf16x8 af[4], bfv[4];
#pragma unroll
    for (int f = 0; f < 4; ++f) {
      af[f]  = *reinterpret_cast<const bf16x8*>(&As[(wm * 64 + f * 16 + lr) * BK + lg * 8]);
      bfv[f] = *reinterpret_cast<const bf16x8*>(&Bs[(wn * 64 + f * 16 + lr) * BK + lg * 8]);
    }
#pragma unroll
    for (int i = 0; i < 4; ++i)
#pragma unroll
      for (int j = 0; j < 4; ++j)
        acc[i][j] = __builtin_amdgcn_mfma_f32_16x16x32_bf16(af[i], bfv[j], acc[i][j], 0, 0, 0);
    __syncthreads();  // all reads done before next stage overwrites
  }

  // ---------------- epilogue ----------------
  float y2v[4];
#pragma unroll
  for (int j = 0; j < 4; ++j) y2v[j] = y2[n0 + wn * 64 + j * 16 + lr];
  float ymin = fminf(fminf(y2v[0], y2v[1]), fminf(y2v[2], y2v[3]));

#pragma unroll
  for (int i = 0; i < 4; ++i) {
    // x2 for the 4 rows this lane owns in fragment-row i
    float xv[4];
#pragma unroll
    for (int r = 0; r < 4; ++r)
      xv[r] = x2[m0 + wm * 64 + i * 16 + lg * 4 + r];
    float xmin = fminf(fminf(xv[0], xv[1]), fminf(xv[2], xv[3]));

    // conservative screen: largest dot product in this lane's 16 elements
    float cmax = acc[i][0][0];
#pragma unroll
    for (int j = 0; j < 4; ++j)
#pragma unroll
      for (int r = 0; r < 4; ++r) cmax = fmaxf(cmax, acc[i][j][r]);

    // d2 >= xmin + ymin - 2*cmax for every element; if that bound is already
    // past the exp-underflow cutoff for every lane, contribution is exactly 0.
    bool maybe = (xmin + ymin - 2.0f * cmax) < EXP_CUTOFF;
    if (__any(maybe)) {
#pragma unroll
      for (int r = 0; r < 4; ++r) {
        int m = m0 + wm * 64 + i * 16 + lg * 4 + r;  // C/D: row=(lane>>4)*4+reg
        float wsp = 0.f, wdp = 0.f;
#pragma unroll
        for (int j = 0; j < 4; ++j) {
          float c = acc[i][j][r];
          float d2 = fmaxf(xv[r] + y2v[j] - 2.0f * c, 0.0f);
          if (d2 < EXP_CUTOFF) {
            float d = sqrtf(d2);
            float w = __expf(-d2);
            wsp += w;
            wdp = fmaf(w, d, wdp);
          }
        }
        // reduce across the 16 lanes sharing this row (same lane>>4)
#pragma unroll
        for (int s = 1; s < 16; s <<= 1) {
          wsp += __shfl_xor(wsp, s, 64);
          wdp += __shfl_xor(wdp, s, 64);
        }
        if (lr == 0) {
          atomicAdd(&wsum[m], wsp);
          atomicAdd(&wdsum[m], wdp);
        }
      }
    }
  }
}

// ------------- finalize: soft-distance, cap, -mean -------------
__global__ __launch_bounds__(256) void finalize(const float* __restrict__ wsum,
                                                const float* __restrict__ wdsum,
                                                float* __restrict__ out, int M) {
  __shared__ float red[256];
  float acc = 0.f;
  for (int r = threadIdx.x; r < M; r += 256) {
    float soft = wdsum[r] / (wsum[r] + EPS);
    acc += fminf(soft, MAX_RADIUS);
  }
  red[threadIdx.x] = acc;
  __syncthreads();
  for (int s = 128; s > 0; s >>= 1) {
    if (threadIdx.x < s) red[threadIdx.x] += red[threadIdx.x + s];
    __syncthreads();
  }
  if (threadIdx.x == 0) out[0] = -red[0] / (float)M;
}

// ------------- workspace-free fallback (insurance if ws too small) -------------
__global__ __launch_bounds__(256) void fallback_row(const float* __restrict__ X,
                                                    const float* __restrict__ Y,
                                                    float* __restrict__ out, int M, int N) {
  __shared__ float xs[D_DIM];
  __shared__ float red[512];
  int b = blockIdx.x;
  for (int i = threadIdx.x; i < D_DIM; i += 256) xs[i] = X[(size_t)b * D_DIM + i];
  __syncthreads();
  float ws = 0.f, wd = 0.f;
  for (int k = threadIdx.x; k < N; k += 256) {
    const float4* y4 = reinterpret_cast<const float4*>(Y + (size_t)k * D_DIM);
    float d2 = 0.f;
#pragma unroll 8
    for (int j = 0; j < D_DIM / 4; ++j) {
      float4 yv = y4[j];
      float4 xv = *reinterpret_cast<const float4*>(&xs[j * 4]);
      float dx = xv.x - yv.x, dy = xv.y - yv.y, dz = xv.z - yv.z, dw = xv.w - yv.w;
      d2 += dx * dx + dy * dy + dz * dz + dw * dw;
    }
    if (d2 < EXP_CUTOFF) {
      float d = sqrtf(d2);
      float w = __expf(-d2);
      ws += w; wd = fmaf(w, d, wd);
    }
  }
  red[threadIdx.x] = ws; red[256 + threadIdx.x] = wd;
  __syncthreads();
  for (int s = 128; s > 0; s >>= 1) {
    if (threadIdx.x < s) {
      red[threadIdx.x] += red[threadIdx.x + s];
      red[256 + threadIdx.x] += red[256 + threadIdx.x + s];
    }
    __syncthreads();
  }
  if (threadIdx.x == 0) {
    float soft = red[256] / (red[0] + EPS);
    atomicAdd(out, -fminf(soft, MAX_RADIUS) / (float)M);
  }
}

extern "C" void kernel_launch(void* const* d_in, const int* in_sizes, int n_in,
                              void* d_out, int out_size, void* d_ws, size_t ws_size,
                              hipStream_t stream) {
  const float* X = (const float*)d_in[0];  // z_generated [M,512]
  const float* Y = (const float*)d_in[1];  // z_known [N,512]
  float* out = (float*)d_out;
  int M = in_sizes[0] / D_DIM;
  int N = in_sizes[1] / D_DIM;

  auto align256 = [](size_t x) { return (x + 255) & ~(size_t)255; };
  size_t oXb = 0;
  size_t oYb = align256(oXb + (size_t)M * D_DIM * 2);
  size_t ox2 = align256(oYb + (size_t)N * D_DIM * 2);
  size_t oy2 = align256(ox2 + (size_t)M * 4);
  size_t ows = align256(oy2 + (size_t)N * 4);
  size_t owd = align256(ows + (size_t)M * 4);
  size_t need = owd + (size_t)M * 4;

  bool fast = (ws_size >= need) && (M % BM == 0) && (N % BN == 0);
  if (fast) {
    char* ws = (char*)d_ws;
    unsigned short* Xb = (unsigned short*)(ws + oXb);
    unsigned short* Yb = (unsigned short*)(ws + oYb);
    float* x2 = (float*)(ws + ox2);
    float* y2 = (float*)(ws + oy2);
    float* wsv = (float*)(ws + ows);
    float* wdv = (float*)(ws + owd);

    zero2_f32<<<(M + 255) / 256, 256, 0, stream>>>(wsv, wdv, M);
    convert_rows<<<(M + 3) / 4, 256, 0, stream>>>(X, Xb, x2, M);
    convert_rows<<<(N + 3) / 4, 256, 0, stream>>>(Y, Yb, y2, N);
    int Mtiles = M / BM, Ntiles = N / BN;
    gemm_epilogue<<<Mtiles * Ntiles, 256, 0, stream>>>(Xb, Yb, x2, y2, wsv, wdv, Ntiles);
    finalize<<<1, 256, 0, stream>>>(wsv, wdv, out, M);
  } else {
    zero_out<<<1, 64, 0, stream>>>(out);
    fallback_row<<<M, 256, 0, stream>>>(X, Y, out, M, N);
  }
}

// Round 3
// 82.187 us; speedup vs baseline: 4.1799x; 1.3687x over previous
//
#include <hip/hip_runtime.h>
#include <stdint.h>

#define D_DIM 512
#define MAX_RADIUS 3.0f
#define EPS 1e-8f

// exp(-d2) in f32 is exactly 0 (even via denormals) once d2 > ~104. Elements
// with d2 >= EXP_CUTOFF contribute exactly 0 to both sums -> skippable.
#define EXP_CUTOFF 104.0f

#define BM 128   // Y-rows (n) per block tile
#define BN 128   // X-rows (m) per block tile
#define BKB 64   // k-bytes (fp8 elems) per K-step

typedef int i32x8 __attribute__((ext_vector_type(8)));
typedef float f32x16 __attribute__((ext_vector_type(16)));

#define GLOBAL_AS __attribute__((address_space(1)))
#define LDS_AS __attribute__((address_space(3)))

// ---------------- zero accumulators ----------------
__global__ void zero2_f32(float* __restrict__ a, float* __restrict__ b, int n) {
  int i = blockIdx.x * blockDim.x + threadIdx.x;
  if (i < n) { a[i] = 0.0f; b[i] = 0.0f; }
}

__global__ void zero_out(float* out) {
  if (threadIdx.x == 0 && blockIdx.x == 0) out[0] = 0.0f;
}

// ------------- f32 -> fp8(e4m3fn) convert + exact f32 row squared-norms -------------
// one wave per row (D=512 -> 8 f32 per lane -> 8 fp8 bytes out)
__global__ __launch_bounds__(256) void convert_fp8(const float* __restrict__ src,
                                                   uint8_t* __restrict__ dst,
                                                   float* __restrict__ norms, int nrows) {
  int wid = threadIdx.x >> 6;
  int lane = threadIdx.x & 63;
  int row = blockIdx.x * 4 + wid;
  if (row >= nrows) return;
  const float4* s4 = reinterpret_cast<const float4*>(src + (size_t)row * D_DIM + lane * 8);
  float4 a = s4[0], b = s4[1];
  float ss = a.x*a.x + a.y*a.y + a.z*a.z + a.w*a.w
           + b.x*b.x + b.y*b.y + b.z*b.z + b.w*b.w;
  // pack 8 fp8 bytes, k ascending in memory
  int lo = __builtin_amdgcn_cvt_pk_fp8_f32(a.x, a.y, 0, 0);
  lo     = __builtin_amdgcn_cvt_pk_fp8_f32(a.z, a.w, lo, 1);
  int hi = __builtin_amdgcn_cvt_pk_fp8_f32(b.x, b.y, 0, 0);
  hi     = __builtin_amdgcn_cvt_pk_fp8_f32(b.z, b.w, hi, 1);
  uint2 o; o.x = (uint32_t)lo; o.y = (uint32_t)hi;
  *reinterpret_cast<uint2*>(dst + (size_t)row * D_DIM + lane * 8) = o;
#pragma unroll
  for (int s = 1; s < 64; s <<= 1) ss += __shfl_xor(ss, s, 64);
  if (lane == 0) norms[row] = ss;
}

// ------------- MX-fp8 MFMA GEMM (Y·X^T) + fused RBF epilogue -------------
// 2-barrier m97 structure, 128x128 tile, 4 waves (2n x 2m), each wave 64x64
// via 2x2 frags of v_mfma_f32_32x32x64_f8f6f4 (scales = 1.0).
// Operands swapped (A=Y) so C: col = m (one per lane), rows = n -> per-m
// reduction is in-lane + one shfl_xor(32).
__global__ __launch_bounds__(256) void gemm_fp8(
    const uint8_t* __restrict__ Yf, const uint8_t* __restrict__ Xf,
    const float* __restrict__ y2, const float* __restrict__ x2,
    float* __restrict__ wsum, float* __restrict__ wdsum, int Mtiles, int Ntiles) {
  __shared__ __align__(16) uint8_t As[BM * BKB];  // Y tile: 128 rows x 64 k-bytes
  __shared__ __align__(16) uint8_t Bs[BN * BKB];  // X tile
  __shared__ float s_y2min[4];

  int nwg = Mtiles * Ntiles;
  int bid = blockIdx.x;
  int swz = bid;
  if ((nwg & 7) == 0) {                 // bijective XCD swizzle (nwg % 8 == 0)
    int chunk = nwg >> 3;
    swz = (bid & 7) * chunk + (bid >> 3);
  }
  int mt = swz % Mtiles;                // consecutive swz share nt -> Y-tile
  int nt = swz / Mtiles;                // stays hot in this XCD's L2
  int n0 = nt * BM, m0 = mt * BN;

  int tid = threadIdx.x;
  int lane = tid & 63;
  int wid = tid >> 6;
  int wn2 = wid >> 1, wm2 = wid & 1;    // wave -> (n-half, m-half)
  int lr = lane & 31, lh = lane >> 5;

  f32x16 acc[2][2];
#pragma unroll
  for (int i = 0; i < 2; ++i)
#pragma unroll
    for (int j = 0; j < 2; ++j)
#pragma unroll
      for (int r = 0; r < 16; ++r) acc[i][j][r] = 0.0f;

  // staging: thread t -> byte t*16 of the 4KB half-tile (row t/4, col (t%4)*16)
  int srow = tid >> 2;
  int scol = (tid & 3) * 16;
  const uint8_t* gY  = Yf + (size_t)(n0 + srow) * D_DIM + scol;
  const uint8_t* gY2 = gY + (size_t)64 * D_DIM;
  const uint8_t* gX  = Xf + (size_t)(m0 + srow) * D_DIM + scol;
  const uint8_t* gX2 = gX + (size_t)64 * D_DIM;
  uint8_t* lA  = &As[srow * BKB + scol];
  uint8_t* lA2 = lA + 64 * BKB;
  uint8_t* lB  = &Bs[srow * BKB + scol];
  uint8_t* lB2 = lB + 64 * BKB;

  for (int k0 = 0; k0 < D_DIM; k0 += BKB) {
    __builtin_amdgcn_global_load_lds((const GLOBAL_AS uint32_t*)gY,  (LDS_AS uint32_t*)lA,  16, 0, 0);
    __builtin_amdgcn_global_load_lds((const GLOBAL_AS uint32_t*)gY2, (LDS_AS uint32_t*)lA2, 16, 0, 0);
    __builtin_amdgcn_global_load_lds((const GLOBAL_AS uint32_t*)gX,  (LDS_AS uint32_t*)lB,  16, 0, 0);
    __builtin_amdgcn_global_load_lds((const GLOBAL_AS uint32_t*)gX2, (LDS_AS uint32_t*)lB2, 16, 0, 0);
    gY += BKB; gY2 += BKB; gX += BKB; gX2 += BKB;
    __syncthreads();  // drains vmcnt -> tiles ready

    i32x8 af[2], bfv[2];
#pragma unroll
    for (int f = 0; f < 2; ++f) {
      // lane: row = f*32 + lr (within wave's 64-strip), k-chunk = lh*32 bytes
      af[f]  = *reinterpret_cast<const i32x8*>(&As[(wn2 * 64 + f * 32 + lr) * BKB + lh * 32]);
      bfv[f] = *reinterpret_cast<const i32x8*>(&Bs[(wm2 * 64 + f * 32 + lr) * BKB + lh * 32]);
    }
#pragma unroll
    for (int i = 0; i < 2; ++i)
#pragma unroll
      for (int j = 0; j < 2; ++j)
        acc[i][j] = __builtin_amdgcn_mfma_scale_f32_32x32x64_f8f6f4(
            af[i], bfv[j], acc[i][j], 0 /*A=fp8*/, 0 /*B=fp8*/, 0, 127, 0, 127);
    __syncthreads();
  }

  // ---------------- epilogue ----------------
  // block-level min of y2 over the 128 n-rows (waves 0/1 cover all 128)
  float yv = y2[n0 + (tid & 127)];
#pragma unroll
  for (int s = 1; s < 64; s <<= 1) yv = fminf(yv, __shfl_xor(yv, s, 64));
  if (lane == 0) s_y2min[wid] = yv;
  __syncthreads();
  float y2min = fminf(fminf(s_y2min[0], s_y2min[1]), fminf(s_y2min[2], s_y2min[3]));

#pragma unroll
  for (int fj = 0; fj < 2; ++fj) {
    int m = m0 + wm2 * 64 + fj * 32 + lr;   // this lane's output column
    float x2m = x2[m];
    float cmax = acc[0][fj][0];
#pragma unroll
    for (int fi = 0; fi < 2; ++fi)
#pragma unroll
      for (int r = 0; r < 16; ++r) cmax = fmaxf(cmax, acc[fi][fj][r]);

    // every element's d2 >= x2m + y2min - 2*cmax; if past cutoff for all
    // lanes, contribution is exactly 0 -> skip loads/exp/atomics entirely.
    bool maybe = (x2m + y2min - 2.0f * cmax) < EXP_CUTOFF;
    if (__any(maybe)) {
      float ws = 0.f, wd = 0.f;
#pragma unroll
      for (int fi = 0; fi < 2; ++fi) {
#pragma unroll
        for (int r = 0; r < 16; ++r) {
          int n = n0 + wn2 * 64 + fi * 32 + (r & 3) + 8 * (r >> 2) + 4 * lh;
          float c = acc[fi][fj][r];
          float d2 = fmaxf(x2m + y2[n] - 2.0f * c, 0.0f);
          if (d2 < EXP_CUTOFF) {
            float d = sqrtf(d2);
            float w = __expf(-d2);
            ws += w;
            wd = fmaf(w, d, wd);
          }
        }
      }
      ws += __shfl_xor(ws, 32, 64);
      wd += __shfl_xor(wd, 32, 64);
      if (lh == 0) {
        atomicAdd(&wsum[m], ws);
        atomicAdd(&wdsum[m], wd);
      }
    }
  }
}

// ------------- finalize: soft-distance, cap, -mean -------------
__global__ __launch_bounds__(256) void finalize(const float* __restrict__ wsum,
                                                const float* __restrict__ wdsum,
                                                float* __restrict__ out, int M) {
  __shared__ float red[256];
  float acc = 0.f;
  for (int r = threadIdx.x; r < M; r += 256) {
    float soft = wdsum[r] / (wsum[r] + EPS);
    acc += fminf(soft, MAX_RADIUS);
  }
  red[threadIdx.x] = acc;
  __syncthreads();
  for (int s = 128; s > 0; s >>= 1) {
    if (threadIdx.x < s) red[threadIdx.x] += red[threadIdx.x + s];
    __syncthreads();
  }
  if (threadIdx.x == 0) out[0] = -red[0] / (float)M;
}

// ------------- workspace-free fallback (insurance if ws too small) -------------
__global__ __launch_bounds__(256) void fallback_row(const float* __restrict__ X,
                                                    const float* __restrict__ Y,
                                                    float* __restrict__ out, int M, int N) {
  __shared__ float xs[D_DIM];
  __shared__ float red[512];
  int b = blockIdx.x;
  for (int i = threadIdx.x; i < D_DIM; i += 256) xs[i] = X[(size_t)b * D_DIM + i];
  __syncthreads();
  float ws = 0.f, wd = 0.f;
  for (int k = threadIdx.x; k < N; k += 256) {
    const float4* y4 = reinterpret_cast<const float4*>(Y + (size_t)k * D_DIM);
    float d2 = 0.f;
#pragma unroll 8
    for (int j = 0; j < D_DIM / 4; ++j) {
      float4 yv = y4[j];
      float4 xv = *reinterpret_cast<const float4*>(&xs[j * 4]);
      float dx = xv.x - yv.x, dy = xv.y - yv.y, dz = xv.z - yv.z, dw = xv.w - yv.w;
      d2 += dx * dx + dy * dy + dz * dz + dw * dw;
    }
    if (d2 < EXP_CUTOFF) {
      float d = sqrtf(d2);
      float w = __expf(-d2);
      ws += w; wd = fmaf(w, d, wd);
    }
  }
  red[threadIdx.x] = ws; red[256 + threadIdx.x] = wd;
  __syncthreads();
  for (int s = 128; s > 0; s >>= 1) {
    if (threadIdx.x < s) {
      red[threadIdx.x] += red[threadIdx.x + s];
      red[256 + threadIdx.x] += red[256 + threadIdx.x + s];
    }
    __syncthreads();
  }
  if (threadIdx.x == 0) {
    float soft = red[256] / (red[0] + EPS);
    atomicAdd(out, -fminf(soft, MAX_RADIUS) / (float)M);
  }
}

extern "C" void kernel_launch(void* const* d_in, const int* in_sizes, int n_in,
                              void* d_out, int out_size, void* d_ws, size_t ws_size,
                              hipStream_t stream) {
  const float* X = (const float*)d_in[0];  // z_generated [M,512]
  const float* Y = (const float*)d_in[1];  // z_known [N,512]
  float* out = (float*)d_out;
  int M = in_sizes[0] / D_DIM;
  int N = in_sizes[1] / D_DIM;

  auto align256 = [](size_t x) { return (x + 255) & ~(size_t)255; };
  size_t oXf = 0;
  size_t oYf = align256(oXf + (size_t)M * D_DIM);
  size_t ox2 = align256(oYf + (size_t)N * D_DIM);
  size_t oy2 = align256(ox2 + (size_t)M * 4);
  size_t ows = align256(oy2 + (size_t)N * 4);
  size_t owd = align256(ows + (size_t)M * 4);
  size_t need = owd + (size_t)M * 4;

  bool fast = (ws_size >= need) && (M % BN == 0) && (N % BM == 0);
  if (fast) {
    char* ws = (char*)d_ws;
    uint8_t* Xf = (uint8_t*)(ws + oXf);
    uint8_t* Yf = (uint8_t*)(ws + oYf);
    float* x2 = (float*)(ws + ox2);
    float* y2 = (float*)(ws + oy2);
    float* wsv = (float*)(ws + ows);
    float* wdv = (float*)(ws + owd);

    zero2_f32<<<(M + 255) / 256, 256, 0, stream>>>(wsv, wdv, M);
    convert_fp8<<<(M + 3) / 4, 256, 0, stream>>>(X, Xf, x2, M);
    convert_fp8<<<(N + 3) / 4, 256, 0, stream>>>(Y, Yf, y2, N);
    int Mtiles = M / BN, Ntiles = N / BM;
    gemm_fp8<<<Mtiles * Ntiles, 256, 0, stream>>>(Yf, Xf, y2, x2, wsv, wdv, Mtiles, Ntiles);
    finalize<<<1, 256, 0, stream>>>(wsv, wdv, out, M);
  } else {
    zero_out<<<1, 64, 0, stream>>>(out);
    fallback_row<<<M, 256, 0, stream>>>(X, Y, out, M, N);
  }
}

// Round 4
// 74.254 us; speedup vs baseline: 4.6265x; 1.1068x over previous
//
#include <hip/hip_runtime.h>
#include <stdint.h>

#define D_DIM 512
#define MAX_RADIUS 3.0f
#define EPS 1e-8f

// exp(-d2) in f32 is exactly 0 (even via denormals) once d2 > ~104. Elements
// with d2 >= EXP_CUTOFF contribute exactly 0 to both sums -> skippable.
#define EXP_CUTOFF 104.0f

#define BM 128   // Y-rows (n) per block tile
#define BN 128   // X-rows (m) per block tile
#define BKB 64   // k-bytes (fp8 elems) per K-step
#define NSTEPS (D_DIM / BKB)

typedef int i32x4 __attribute__((ext_vector_type(4)));
typedef int i32x8 __attribute__((ext_vector_type(8)));
typedef float f32x16 __attribute__((ext_vector_type(16)));

#define GLOBAL_AS __attribute__((address_space(1)))
#define LDS_AS __attribute__((address_space(3)))

static __device__ __forceinline__ i32x8 cat8(i32x4 lo, i32x4 hi) {
  i32x8 v;
  v[0] = lo[0]; v[1] = lo[1]; v[2] = lo[2]; v[3] = lo[3];
  v[4] = hi[0]; v[5] = hi[1]; v[6] = hi[2]; v[7] = hi[3];
  return v;
}

__global__ void zero_out(float* out) {
  if (threadIdx.x == 0 && blockIdx.x == 0) out[0] = 0.0f;
}

// ------------- f32 -> fp8(e4m3fn) convert + exact f32 row squared-norms -------------
// one wave per row (D=512 -> 8 f32 per lane -> 8 fp8 bytes out).
// za/zb (optional): per-row accumulators to zero (folds the zero kernel).
__global__ __launch_bounds__(256) void convert_fp8(const float* __restrict__ src,
                                                   uint8_t* __restrict__ dst,
                                                   float* __restrict__ norms, int nrows,
                                                   float* __restrict__ za,
                                                   float* __restrict__ zb) {
  int wid = threadIdx.x >> 6;
  int lane = threadIdx.x & 63;
  int row = blockIdx.x * 4 + wid;
  if (row >= nrows) return;
  const float4* s4 = reinterpret_cast<const float4*>(src + (size_t)row * D_DIM + lane * 8);
  float4 a = s4[0], b = s4[1];
  float ss = a.x*a.x + a.y*a.y + a.z*a.z + a.w*a.w
           + b.x*b.x + b.y*b.y + b.z*b.z + b.w*b.w;
  int lo = __builtin_amdgcn_cvt_pk_fp8_f32(a.x, a.y, 0, 0);
  lo     = __builtin_amdgcn_cvt_pk_fp8_f32(a.z, a.w, lo, 1);
  int hi = __builtin_amdgcn_cvt_pk_fp8_f32(b.x, b.y, 0, 0);
  hi     = __builtin_amdgcn_cvt_pk_fp8_f32(b.z, b.w, hi, 1);
  uint2 o; o.x = (uint32_t)lo; o.y = (uint32_t)hi;
  *reinterpret_cast<uint2*>(dst + (size_t)row * D_DIM + lane * 8) = o;
#pragma unroll
  for (int s = 1; s < 64; s <<= 1) ss += __shfl_xor(ss, s, 64);
  if (lane == 0) {
    norms[row] = ss;
    if (za) { za[row] = 0.0f; zb[row] = 0.0f; }
  }
}

// ------------- MX-fp8 MFMA GEMM (Y·X^T) + fused RBF epilogue -------------
// 2-phase double-buffered 128x128 tile, ONE barrier per K-step; staging for
// tile t+1 issued before tile t's ds_reads so HBM latency hides under MFMA.
// LDS 16B-chunk XOR swizzle (chunk ^= (row>>1)&3): dest linear (gload_lds),
// global source pre-swizzled, reads apply the same involution -> all 32 banks.
// Operands swapped (A=Y) so C: col = m (one per lane), rows = n -> per-m
// reduction is in-lane + one shfl_xor(32).
__global__ __launch_bounds__(256) void gemm_fp8(
    const uint8_t* __restrict__ Yf, const uint8_t* __restrict__ Xf,
    const float* __restrict__ y2, const float* __restrict__ x2,
    float* __restrict__ wsum, float* __restrict__ wdsum, int Mtiles, int Ntiles) {
  __shared__ __align__(16) uint8_t As[2][BM * BKB];  // Y tiles
  __shared__ __align__(16) uint8_t Bs[2][BN * BKB];  // X tiles
  __shared__ float s_y2min[4];

  int nwg = Mtiles * Ntiles;
  int bid = blockIdx.x;
  int swz = bid;
  if ((nwg & 7) == 0) {                 // bijective XCD swizzle (nwg % 8 == 0)
    int chunk = nwg >> 3;
    swz = (bid & 7) * chunk + (bid >> 3);
  }
  int mt = swz % Mtiles;                // consecutive swz share nt -> Y-tile
  int nt = swz / Mtiles;                // stays hot in this XCD's L2
  int n0 = nt * BM, m0 = mt * BN;

  int tid = threadIdx.x;
  int lane = tid & 63;
  int wid = tid >> 6;
  int wn2 = wid >> 1, wm2 = wid & 1;    // wave -> (n-half, m-half)
  int lr = lane & 31, lh = lane >> 5;

  f32x16 acc[2][2];
#pragma unroll
  for (int i = 0; i < 2; ++i)
#pragma unroll
    for (int j = 0; j < 2; ++j)
#pragma unroll
      for (int r = 0; r < 16; ++r) acc[i][j][r] = 0.0f;

  // ---- staging map: thread t -> LDS byte t*16 (row t>>2, pos t&3), halves
  // at +4096. Source chunk pre-swizzled: schunk = pos ^ ((row>>1)&3).
  int srow = tid >> 2;
  int spos = tid & 3;
  int schunk = spos ^ ((srow >> 1) & 3);
  const uint8_t* gY  = Yf + (size_t)(n0 + srow) * D_DIM + schunk * 16;
  const uint8_t* gY2 = gY + (size_t)64 * D_DIM;   // rows 64-127: same swizzle phase
  const uint8_t* gX  = Xf + (size_t)(m0 + srow) * D_DIM + schunk * 16;
  const uint8_t* gX2 = gX + (size_t)64 * D_DIM;
  int l0 = tid * 16;

#define STAGE(buf, step)                                                                               \
  do {                                                                                                 \
    __builtin_amdgcn_global_load_lds((const GLOBAL_AS uint32_t*)(gY  + (step) * BKB),                  \
                                     (LDS_AS uint32_t*)&As[(buf)][l0], 16, 0, 0);                      \
    __builtin_amdgcn_global_load_lds((const GLOBAL_AS uint32_t*)(gY2 + (step) * BKB),                  \
                                     (LDS_AS uint32_t*)&As[(buf)][l0 + 4096], 16, 0, 0);               \
    __builtin_amdgcn_global_load_lds((const GLOBAL_AS uint32_t*)(gX  + (step) * BKB),                  \
                                     (LDS_AS uint32_t*)&Bs[(buf)][l0], 16, 0, 0);                      \
    __builtin_amdgcn_global_load_lds((const GLOBAL_AS uint32_t*)(gX2 + (step) * BKB),                  \
                                     (LDS_AS uint32_t*)&Bs[(buf)][l0 + 4096], 16, 0, 0);               \
  } while (0)

  STAGE(0, 0);
  int cur = 0;
  // read-side swizzle: row = wn2*64 + f*32 + lr -> (row>>1)&3 == (lr>>1)&3
  int sw = (lr >> 1) & 3;
  int cA = ((2 * lh) ^ sw) * 16;  // LDS byte offset of logical chunk 2*lh
  int cB = cA ^ 16;               // logical chunk 2*lh+1

  for (int t = 0; t < NSTEPS; ++t) {
    __syncthreads();  // drains vmcnt: buf[cur] staged; prior buf readers done
    if (t + 1 < NSTEPS) STAGE(cur ^ 1, t + 1);

    const uint8_t* A = As[cur];
    const uint8_t* B = Bs[cur];
    i32x8 af[2], bfv[2];
#pragma unroll
    for (int f = 0; f < 2; ++f) {
      const uint8_t* ra = A + (wn2 * 64 + f * 32 + lr) * BKB;
      const uint8_t* rb = B + (wm2 * 64 + f * 32 + lr) * BKB;
      i32x4 alo = *(const i32x4*)(ra + cA);
      i32x4 ahi = *(const i32x4*)(ra + cB);
      i32x4 blo = *(const i32x4*)(rb + cA);
      i32x4 bhi = *(const i32x4*)(rb + cB);
      af[f]  = cat8(alo, ahi);
      bfv[f] = cat8(blo, bhi);
    }
#pragma unroll
    for (int i = 0; i < 2; ++i)
#pragma unroll
      for (int j = 0; j < 2; ++j)
        acc[i][j] = __builtin_amdgcn_mfma_scale_f32_32x32x64_f8f6f4(
            af[i], bfv[j], acc[i][j], 0 /*A=fp8*/, 0 /*B=fp8*/, 0, 127, 0, 127);
    cur ^= 1;
  }
#undef STAGE

  // ---------------- epilogue ----------------
  // block-level min of y2 over the 128 n-rows (waves 0/1 cover all 128)
  float yv = y2[n0 + (tid & 127)];
#pragma unroll
  for (int s = 1; s < 64; s <<= 1) yv = fminf(yv, __shfl_xor(yv, s, 64));
  if (lane == 0) s_y2min[wid] = yv;
  __syncthreads();
  float y2min = fminf(fminf(s_y2min[0], s_y2min[1]), fminf(s_y2min[2], s_y2min[3]));

#pragma unroll
  for (int fj = 0; fj < 2; ++fj) {
    int m = m0 + wm2 * 64 + fj * 32 + lr;   // this lane's output column
    float x2m = x2[m];
    float cmax = acc[0][fj][0];
#pragma unroll
    for (int fi = 0; fi < 2; ++fi)
#pragma unroll
      for (int r = 0; r < 16; ++r) cmax = fmaxf(cmax, acc[fi][fj][r]);

    // every element's d2 >= x2m + y2min - 2*cmax; if past cutoff for all
    // lanes, contribution is exactly 0 -> skip loads/exp/atomics entirely.
    bool maybe = (x2m + y2min - 2.0f * cmax) < EXP_CUTOFF;
    if (__any(maybe)) {
      float ws = 0.f, wd = 0.f;
#pragma unroll
      for (int fi = 0; fi < 2; ++fi) {
#pragma unroll
        for (int r = 0; r < 16; ++r) {
          int n = n0 + wn2 * 64 + fi * 32 + (r & 3) + 8 * (r >> 2) + 4 * lh;
          float c = acc[fi][fj][r];
          float d2 = fmaxf(x2m + y2[n] - 2.0f * c, 0.0f);
          if (d2 < EXP_CUTOFF) {
            float d = sqrtf(d2);
            float w = __expf(-d2);
            ws += w;
            wd = fmaf(w, d, wd);
          }
        }
      }
      ws += __shfl_xor(ws, 32, 64);
      wd += __shfl_xor(wd, 32, 64);
      if (lh == 0) {
        atomicAdd(&wsum[m], ws);
        atomicAdd(&wdsum[m], wd);
      }
    }
  }
}

// ------------- finalize: soft-distance, cap, -mean -------------
__global__ __launch_bounds__(256) void finalize(const float* __restrict__ wsum,
                                                const float* __restrict__ wdsum,
                                                float* __restrict__ out, int M) {
  __shared__ float red[256];
  float acc = 0.f;
  for (int r = threadIdx.x; r < M; r += 256) {
    float soft = wdsum[r] / (wsum[r] + EPS);
    acc += fminf(soft, MAX_RADIUS);
  }
  red[threadIdx.x] = acc;
  __syncthreads();
  for (int s = 128; s > 0; s >>= 1) {
    if (threadIdx.x < s) red[threadIdx.x] += red[threadIdx.x + s];
    __syncthreads();
  }
  if (threadIdx.x == 0) out[0] = -red[0] / (float)M;
}

// ------------- workspace-free fallback (insurance if ws too small) -------------
__global__ __launch_bounds__(256) void fallback_row(const float* __restrict__ X,
                                                    const float* __restrict__ Y,
                                                    float* __restrict__ out, int M, int N) {
  __shared__ float xs[D_DIM];
  __shared__ float red[512];
  int b = blockIdx.x;
  for (int i = threadIdx.x; i < D_DIM; i += 256) xs[i] = X[(size_t)b * D_DIM + i];
  __syncthreads();
  float ws = 0.f, wd = 0.f;
  for (int k = threadIdx.x; k < N; k += 256) {
    const float4* y4 = reinterpret_cast<const float4*>(Y + (size_t)k * D_DIM);
    float d2 = 0.f;
#pragma unroll 8
    for (int j = 0; j < D_DIM / 4; ++j) {
      float4 yv = y4[j];
      float4 xv = *reinterpret_cast<const float4*>(&xs[j * 4]);
      float dx = xv.x - yv.x, dy = xv.y - yv.y, dz = xv.z - yv.z, dw = xv.w - yv.w;
      d2 += dx * dx + dy * dy + dz * dz + dw * dw;
    }
    if (d2 < EXP_CUTOFF) {
      float d = sqrtf(d2);
      float w = __expf(-d2);
      ws += w; wd = fmaf(w, d, wd);
    }
  }
  red[threadIdx.x] = ws; red[256 + threadIdx.x] = wd;
  __syncthreads();
  for (int s = 128; s > 0; s >>= 1) {
    if (threadIdx.x < s) {
      red[threadIdx.x] += red[threadIdx.x + s];
      red[256 + threadIdx.x] += red[256 + threadIdx.x + s];
    }
    __syncthreads();
  }
  if (threadIdx.x == 0) {
    float soft = red[256] / (red[0] + EPS);
    atomicAdd(out, -fminf(soft, MAX_RADIUS) / (float)M);
  }
}

extern "C" void kernel_launch(void* const* d_in, const int* in_sizes, int n_in,
                              void* d_out, int out_size, void* d_ws, size_t ws_size,
                              hipStream_t stream) {
  const float* X = (const float*)d_in[0];  // z_generated [M,512]
  const float* Y = (const float*)d_in[1];  // z_known [N,512]
  float* out = (float*)d_out;
  int M = in_sizes[0] / D_DIM;
  int N = in_sizes[1] / D_DIM;

  auto align256 = [](size_t x) { return (x + 255) & ~(size_t)255; };
  size_t oXf = 0;
  size_t oYf = align256(oXf + (size_t)M * D_DIM);
  size_t ox2 = align256(oYf + (size_t)N * D_DIM);
  size_t oy2 = align256(ox2 + (size_t)M * 4);
  size_t ows = align256(oy2 + (size_t)N * 4);
  size_t owd = align256(ows + (size_t)M * 4);
  size_t need = owd + (size_t)M * 4;

  bool fast = (ws_size >= need) && (M % BN == 0) && (N % BM == 0);
  if (fast) {
    char* ws = (char*)d_ws;
    uint8_t* Xf = (uint8_t*)(ws + oXf);
    uint8_t* Yf = (uint8_t*)(ws + oYf);
    float* x2 = (float*)(ws + ox2);
    float* y2 = (float*)(ws + oy2);
    float* wsv = (float*)(ws + ows);
    float* wdv = (float*)(ws + owd);

    convert_fp8<<<(M + 3) / 4, 256, 0, stream>>>(X, Xf, x2, M, wsv, wdv);
    convert_fp8<<<(N + 3) / 4, 256, 0, stream>>>(Y, Yf, y2, N, nullptr, nullptr);
    int Mtiles = M / BN, Ntiles = N / BM;
    gemm_fp8<<<Mtiles * Ntiles, 256, 0, stream>>>(Yf, Xf, y2, x2, wsv, wdv, Mtiles, Ntiles);
    finalize<<<1, 256, 0, stream>>>(wsv, wdv, out, M);
  } else {
    zero_out<<<1, 64, 0, stream>>>(out);
    fallback_row<<<M, 256, 0, stream>>>(X, Y, out, M, N);
  }
}